// Round 4
// baseline (510.954 us; speedup 1.0000x reference)
//
#include <hip/hip_runtime.h>
#include <stdint.h>

// Problem constants
#define DN 256   // D
#define N2C 512  // N2 (= E)
#define TC 4096  // T
#define EC 512   // E

// prep_fused grid: bids [0,2048) interleave 4 jobs (k1,k2b,p2,p3) x 512 each;
// bids [2048,2112) = k2a colsum. Interleave keeps every CU on a mix so the
// A1/A2/A3 streams overlap the dominant W2/R2 stream.
#define B_MIX_END 2048
#define B_TOTAL   2112

// ---------------------------------------------------------------------------
// prep_fused jobs:
//  k1 : new2[j,d] = sum_i x2[i,d]*W2[j,i,d] + sum_i R2[j,i,d] + x2[j,d]
//       8 waves; wave g handles i = it*8+g so the block streams W2/R2 rows
//       CONTIGUOUSLY (8 consecutive 1KB lines per step) -> 2 streams/block.
//  k2b: deg1[row] = 1 + nnz(A1[row,:])
//  p2 : PT2[t][w] bit b = (A2[w*32+b][t] != 0), w in [0,16)
//  p3 : PT3[e][w] bit b = (A3[w*32+b][e] != 0), w in [0,128)
//  k2a: S[d] = colsum of emb rows 512..4607 (atomicAdd into zeroed S)
// ---------------------------------------------------------------------------
__global__ __launch_bounds__(512) void prep_fused(
    const float* __restrict__ emb, const float* __restrict__ W2,
    const float* __restrict__ R2, const int* __restrict__ A1,
    const int* __restrict__ A2, const int* __restrict__ A3,
    float* __restrict__ out, float* __restrict__ S,
    float* __restrict__ deg1, uint32_t* __restrict__ PT2,
    uint32_t* __restrict__ PT3)
{
    __shared__ __align__(16) char smem[64 * 65 * 4];  // union: ldsb / red
    uint32_t (*ldsb)[65] = (uint32_t (*)[65])smem;
    float4   (*red)[64]  = (float4 (*)[64])smem;

    const int bid = blockIdx.x;
    const int tid = threadIdx.x;

    if (bid < B_MIX_END) {
        const int job = bid & 3;
        const int sub = bid >> 2;  // 0..511

        if (job == 0) {
            // ---- k1 ----
            const int d4  = tid & 63;
            const int grp = tid >> 6;   // 0..7
            const int j   = sub;
            const float4* W = (const float4*)(W2 + (size_t)j * N2C * DN);
            const float4* R = (const float4*)(R2 + (size_t)j * N2C * DN);
            const float4* X = (const float4*)emb;

            const int base = grp * 64 + d4;
            float4 aw = {0.f, 0.f, 0.f, 0.f};
            float4 ar = {0.f, 0.f, 0.f, 0.f};
            #pragma unroll 4
            for (int it = 0; it < 64; ++it) {
                const int idx = it * 512 + base;   // i = it*8+grp
                float4 w = W[idx];
                float4 r = R[idx];
                float4 x = X[idx];
                aw.x = fmaf(x.x, w.x, aw.x);
                aw.y = fmaf(x.y, w.y, aw.y);
                aw.z = fmaf(x.z, w.z, aw.z);
                aw.w = fmaf(x.w, w.w, aw.w);
                ar.x += r.x; ar.y += r.y; ar.z += r.z; ar.w += r.w;
            }
            float4 mine;
            mine.x = aw.x + ar.x; mine.y = aw.y + ar.y;
            mine.z = aw.z + ar.z; mine.w = aw.w + ar.w;
            red[grp][d4] = mine;
            __syncthreads();
            if (grp == 0) {
                float sx = 0.f, sy = 0.f, sz = 0.f, sw = 0.f;
                #pragma unroll
                for (int g = 0; g < 8; ++g) {
                    float4 v = red[g][d4];
                    sx += v.x; sy += v.y; sz += v.z; sw += v.w;
                }
                float4 x = X[j * 64 + d4];
                float4 o;
                o.x = sx + x.x; o.y = sy + x.y;
                o.z = sz + x.z; o.w = sw + x.w;
                ((float4*)out)[j * 64 + d4] = o;
            }
        } else if (job == 1) {
            // ---- k2b ----
            const int row  = sub * 8 + (tid >> 6);
            const int lane = tid & 63;
            const int4* p = (const int4*)(A1 + (size_t)row * TC);
            int cnt = 0;
            #pragma unroll
            for (int k = 0; k < 16; ++k) {
                int4 v = p[k * 64 + lane];
                cnt += (v.x != 0) + (v.y != 0) + (v.z != 0) + (v.w != 0);
            }
            #pragma unroll
            for (int off = 32; off > 0; off >>= 1) cnt += __shfl_down(cnt, off, 64);
            if (lane == 0) deg1[row] = 1.0f + (float)cnt;
        } else if (job == 2) {
            // ---- p2 ----
            const int e0 = (sub & 7) * 64;
            const int t0 = (sub >> 3) * 64;
            const int tx = tid & 63;
            const int ty = tid >> 6;  // 0..7
            #pragma unroll
            for (int k = 0; k < 8; ++k) {
                int el = ty * 8 + k;
                ldsb[el][tx] = (A2[(size_t)(e0 + el) * TC + t0 + tx] != 0) ? 1u : 0u;
            }
            __syncthreads();
            if (tid < 128) {
                const int tl = tid & 63;
                const int w  = tid >> 6;
                uint32_t bits = 0;
                #pragma unroll
                for (int b = 0; b < 32; ++b) bits |= ldsb[w * 32 + b][tl] << b;
                PT2[(size_t)(t0 + tl) * 16 + (e0 >> 5) + w] = bits;
            }
        } else {
            // ---- p3 ----
            const int t0 = (sub >> 3) * 64;
            const int e0 = (sub & 7) * 64;
            const int ex = tid & 63;
            const int ty = tid >> 6;  // 0..7
            #pragma unroll
            for (int k = 0; k < 8; ++k) {
                int tl = ty * 8 + k;
                ldsb[tl][ex] = (A3[(size_t)(t0 + tl) * EC + e0 + ex] != 0) ? 1u : 0u;
            }
            __syncthreads();
            if (tid < 128) {
                const int el = tid & 63;
                const int w  = tid >> 6;
                uint32_t bits = 0;
                #pragma unroll
                for (int b = 0; b < 32; ++b) bits |= ldsb[w * 32 + b][el] << b;
                PT3[(size_t)(e0 + el) * 128 + (t0 >> 5) + w] = bits;
            }
        }
    } else {
        // ---- k2a ----
        const int b = bid - B_MIX_END;
        const int d = tid & 255;
        const int h = tid >> 8;  // 0 or 1
        const float* base = emb + (size_t)N2C * DN;
        const int r0 = b * 64 + h * 32;
        float s = 0.f;
        #pragma unroll 4
        for (int r = r0; r < r0 + 32; ++r) s += base[(size_t)r * DN + d];
        atomicAdd(&S[d], s);
    }
}

// ---------------------------------------------------------------------------
// k3_dense: new_common[t,d] = (sub+S)*(1 - S/deg1) + A2f^T@new2 + (512-deg2)
// Block 256 thr = 4 wave-groups x 64 d4; each group owns 8 t. Grid 128.
// Per e-row: one coalesced 1KB spec load serves 32 FMAs (8 t x 4 comps).
// ---------------------------------------------------------------------------
__global__ __launch_bounds__(256) void k3_dense(
    const float* __restrict__ emb, const uint32_t* __restrict__ PT2,
    const float* __restrict__ S, const float* __restrict__ deg1,
    float* out)
{
    const int d4 = threadIdx.x & 63;
    const int tg = threadIdx.x >> 6;
    const int t0 = blockIdx.x * 32 + tg * 8;
    const float4* spec = (const float4*)out;  // new2, rows 0..511

    float4 acc[8];
    int cnt[8];
    #pragma unroll
    for (int k = 0; k < 8; ++k) { acc[k] = make_float4(0.f,0.f,0.f,0.f); cnt[k] = 0; }

    for (int ec = 0; ec < 16; ++ec) {
        uint32_t m[8];
        #pragma unroll
        for (int k = 0; k < 8; ++k) {
            m[k] = PT2[(size_t)(t0 + k) * 16 + ec];
            cnt[k] += __popc(m[k]);
        }
        const float4* sp = spec + (size_t)ec * 32 * 64 + d4;
        #pragma unroll
        for (int b = 0; b < 32; ++b) {
            float4 v = sp[b * 64];
            #pragma unroll
            for (int k = 0; k < 8; ++k) {
                float f = (float)((m[k] >> b) & 1u);
                acc[k].x = fmaf(f, v.x, acc[k].x);
                acc[k].y = fmaf(f, v.y, acc[k].y);
                acc[k].z = fmaf(f, v.z, acc[k].z);
                acc[k].w = fmaf(f, v.w, acc[k].w);
            }
        }
    }

    const float4 Sv = ((const float4*)S)[d4];
    #pragma unroll
    for (int k = 0; k < 8; ++k) {
        const int t = t0 + k;
        const float inv = 1.0f / deg1[t];
        const float addc = (float)(EC - cnt[k]);
        const float4 sub = ((const float4*)emb)[(size_t)(N2C + t) * 64 + d4];
        float4 o;
        o.x = (sub.x + Sv.x) * (1.0f - Sv.x * inv) + acc[k].x + addc;
        o.y = (sub.y + Sv.y) * (1.0f - Sv.y * inv) + acc[k].y + addc;
        o.z = (sub.z + Sv.z) * (1.0f - Sv.z * inv) + acc[k].z + addc;
        o.w = (sub.w + Sv.w) * (1.0f - Sv.w * inv) + acc[k].w + addc;
        ((float4*)out)[(size_t)(N2C + t) * 64 + d4] = o;
    }
}

// ---------------------------------------------------------------------------
// k4_part: P[chunk][e][d] = sum over chunk's 1024 t of bit3(t,e)*nc[t][d].
// Block 256 thr = 4 wave-groups x 64 d4; each group owns 8 e.
// Grid = 16 e-tiles x 4 chunks = 64 blocks.
// ---------------------------------------------------------------------------
__global__ __launch_bounds__(256) void k4_part(
    const uint32_t* __restrict__ PT3, const float* __restrict__ out,
    float* __restrict__ P)
{
    const int d4    = threadIdx.x & 63;
    const int es    = threadIdx.x >> 6;   // 0..3
    const int etile = blockIdx.x >> 2;    // 0..15
    const int chunk = blockIdx.x & 3;     // 0..3
    const int e0 = etile * 32 + es * 8;
    const float4* nc = (const float4*)(out + (size_t)N2C * DN);

    float4 acc[8];
    #pragma unroll
    for (int k = 0; k < 8; ++k) acc[k] = make_float4(0.f,0.f,0.f,0.f);

    for (int w = 0; w < 32; ++w) {
        uint32_t m[8];
        #pragma unroll
        for (int k = 0; k < 8; ++k)
            m[k] = PT3[(size_t)(e0 + k) * 128 + chunk * 32 + w];
        const float4* np = nc + (size_t)((chunk * 32 + w) * 32) * 64 + d4;
        #pragma unroll
        for (int b = 0; b < 32; ++b) {
            float4 v = np[b * 64];
            #pragma unroll
            for (int k = 0; k < 8; ++k) {
                float f = (float)((m[k] >> b) & 1u);
                acc[k].x = fmaf(f, v.x, acc[k].x);
                acc[k].y = fmaf(f, v.y, acc[k].y);
                acc[k].z = fmaf(f, v.z, acc[k].z);
                acc[k].w = fmaf(f, v.w, acc[k].w);
            }
        }
    }
    float4* Pp = (float4*)P;
    #pragma unroll
    for (int k = 0; k < 8; ++k)
        Pp[((size_t)chunk * EC + e0 + k) * 64 + d4] = acc[k];
}

// ---------------------------------------------------------------------------
// k4_fin: combine 4 partials, deg3 via popcount of PT3[e][*],
// new_spec[e,d] = new2[e,d]*(1 - (msg3+4096-deg3)/(1+deg3)). Wave per e.
// ---------------------------------------------------------------------------
__global__ __launch_bounds__(256) void k4_fin(
    const uint32_t* __restrict__ PT3, const float* __restrict__ P,
    float* out)
{
    const int d4 = threadIdx.x & 63;
    const int es = threadIdx.x >> 6;
    const int e  = blockIdx.x * 4 + es;
    const float4* Pp = (const float4*)P;

    float4 s0 = Pp[((size_t)0 * EC + e) * 64 + d4];
    float4 s1 = Pp[((size_t)1 * EC + e) * 64 + d4];
    float4 s2 = Pp[((size_t)2 * EC + e) * 64 + d4];
    float4 s3 = Pp[((size_t)3 * EC + e) * 64 + d4];
    float4 s;
    s.x = s0.x + s1.x + s2.x + s3.x;
    s.y = s0.y + s1.y + s2.y + s3.y;
    s.z = s0.z + s1.z + s2.z + s3.z;
    s.w = s0.w + s1.w + s2.w + s3.w;

    int c = __popc(PT3[(size_t)e * 128 + 2 * d4]) +
            __popc(PT3[(size_t)e * 128 + 2 * d4 + 1]);
    #pragma unroll
    for (int off = 32; off > 0; off >>= 1) c += __shfl_xor(c, off, 64);

    const float msg_add = (float)(TC - c);
    const float inv = 1.0f / (1.0f + (float)c);
    float4 cur = ((const float4*)out)[(size_t)e * 64 + d4];
    float4 o;
    o.x = cur.x * (1.0f - (s.x + msg_add) * inv);
    o.y = cur.y * (1.0f - (s.y + msg_add) * inv);
    o.z = cur.z * (1.0f - (s.z + msg_add) * inv);
    o.w = cur.w * (1.0f - (s.w + msg_add) * inv);
    ((float4*)out)[(size_t)e * 64 + d4] = o;
}

extern "C" void kernel_launch(void* const* d_in, const int* in_sizes, int n_in,
                              void* d_out, int out_size, void* d_ws, size_t ws_size,
                              hipStream_t stream) {
    const float* emb = (const float*)d_in[0];
    const float* W2  = (const float*)d_in[1];
    const float* R2  = (const float*)d_in[2];
    const int*   A1  = (const int*)d_in[3];
    const int*   A2  = (const int*)d_in[4];
    const int*   A3  = (const int*)d_in[5];
    float* out = (float*)d_out;

    float*    S    = (float*)d_ws;                    // 256 floats
    float*    deg1 = S + DN;                          // 4096 floats
    uint32_t* PT2  = (uint32_t*)(deg1 + TC);          // 4096*16 words (256 KB)
    uint32_t* PT3  = PT2 + (size_t)TC * 16;           // 512*128 words (256 KB)
    float*    P    = (float*)(PT3 + (size_t)EC * 128);// 4*512*256 floats (2 MB)

    hipMemsetAsync(d_ws, 0, DN * sizeof(float), stream);

    prep_fused<<<B_TOTAL, 512, 0, stream>>>(emb, W2, R2, A1, A2, A3,
                                            out, S, deg1, PT2, PT3);
    k3_dense<<<TC / 32, 256, 0, stream>>>(emb, PT2, S, deg1, out);
    k4_part<<<64, 256, 0, stream>>>(PT3, out, P);
    k4_fin<<<EC / 4, 256, 0, stream>>>(PT3, P, out);
}

// Round 5
// 215.887 us; speedup vs baseline: 2.3668x; 2.3668x over previous
//
#include <hip/hip_runtime.h>
#include <stdint.h>

// Problem constants
#define DN 256   // D
#define N2C 512  // N2 (= E)
#define TC 4096  // T
#define EC 512   // E

// Grid: 512 k1 blocks + 256 A-blocks, all 512 threads. Dispatch order gives
// each CU ~2 k1 blocks + 1 A-block co-resident, so the 80 MB A1/A2/A3 streams
// overlap the 512 MB W2/R2 stream instead of running as a serial tail.
#define B_K1 512
#define B_A  256

// ---------------------------------------------------------------------------
// prep_fused:
//  k1-block j : new2[j,d] = sum_i x2[i,d]*W2[j,i,d] + sum_i R2[j,i,d] + x2[j,d]
//               wave g owns i in [g*64,(g+1)*64) sequentially (per-wave
//               contiguous 64KB stream — round-2 proven layout).
//  A-block ab : 16 rows of k2b (deg1), 2 tiles of p2 (PT2), 2 tiles of p3
//               (PT3), 16 rows of k2a colsum (S, atomicAdd into zeroed S).
// ---------------------------------------------------------------------------
__global__ __launch_bounds__(512) void prep_fused(
    const float* __restrict__ emb, const float* __restrict__ W2,
    const float* __restrict__ R2, const int* __restrict__ A1,
    const int* __restrict__ A2, const int* __restrict__ A3,
    float* __restrict__ out, float* __restrict__ S,
    float* __restrict__ deg1, uint32_t* __restrict__ PT2,
    uint32_t* __restrict__ PT3)
{
    __shared__ __align__(16) char smem[64 * 65 * 4];  // union: ldsb / red
    uint32_t (*ldsb)[65] = (uint32_t (*)[65])smem;
    float4   (*red)[64]  = (float4 (*)[64])smem;

    const int bid = blockIdx.x;
    const int tid = threadIdx.x;

    if (bid < B_K1) {
        // ---- k1 ----
        const int d4  = tid & 63;
        const int grp = tid >> 6;
        const int j   = bid;
        const float4* W = (const float4*)(W2 + (size_t)j * N2C * DN);
        const float4* R = (const float4*)(R2 + (size_t)j * N2C * DN);
        const float4* X = (const float4*)emb;

        float ax = 0.f, ay = 0.f, az = 0.f, aw = 0.f;
        const int i0 = grp * 64;
        #pragma unroll 4
        for (int i = i0; i < i0 + 64; ++i) {
            float4 w = W[i * 64 + d4];
            float4 r = R[i * 64 + d4];
            float4 x = X[i * 64 + d4];
            ax += x.x * w.x + r.x;
            ay += x.y * w.y + r.y;
            az += x.z * w.z + r.z;
            aw += x.w * w.w + r.w;
        }
        float4 mine; mine.x = ax; mine.y = ay; mine.z = az; mine.w = aw;
        red[grp][d4] = mine;
        __syncthreads();
        if (grp == 0) {
            float sx = 0.f, sy = 0.f, sz = 0.f, sw = 0.f;
            #pragma unroll
            for (int g = 0; g < 8; ++g) {
                float4 v = red[g][d4];
                sx += v.x; sy += v.y; sz += v.z; sw += v.w;
            }
            float4 x = X[j * 64 + d4];
            float4 o;
            o.x = sx + x.x; o.y = sy + x.y; o.z = sz + x.z; o.w = sw + x.w;
            ((float4*)out)[j * 64 + d4] = o;
        }
    } else {
        const int ab = bid - B_K1;  // 0..255

        // ---- k2b: deg1 for 16 rows (wave per row, 2 passes) ----
        {
            const int lane = tid & 63;
            #pragma unroll
            for (int it = 0; it < 2; ++it) {
                const int row = ab * 16 + it * 8 + (tid >> 6);
                const int4* p = (const int4*)(A1 + (size_t)row * TC);
                int cnt = 0;
                #pragma unroll
                for (int k = 0; k < 16; ++k) {
                    int4 v = p[k * 64 + lane];
                    cnt += (v.x != 0) + (v.y != 0) + (v.z != 0) + (v.w != 0);
                }
                #pragma unroll
                for (int off = 32; off > 0; off >>= 1)
                    cnt += __shfl_down(cnt, off, 64);
                if (lane == 0) deg1[row] = 1.0f + (float)cnt;
            }
        }

        // ---- p2: 2 tiles ----
        #pragma unroll
        for (int pt = 0; pt < 2; ++pt) {
            const int sub = ab * 2 + pt;
            const int e0 = (sub & 7) * 64;
            const int t0 = (sub >> 3) * 64;
            const int tx = tid & 63;
            const int ty = tid >> 6;
            #pragma unroll
            for (int k = 0; k < 8; ++k) {
                int el = ty * 8 + k;
                ldsb[el][tx] = (A2[(size_t)(e0 + el) * TC + t0 + tx] != 0) ? 1u : 0u;
            }
            __syncthreads();
            if (tid < 128) {
                const int tl = tid & 63;
                const int w  = tid >> 6;
                uint32_t bits = 0;
                #pragma unroll
                for (int b = 0; b < 32; ++b) bits |= ldsb[w * 32 + b][tl] << b;
                PT2[(size_t)(t0 + tl) * 16 + (e0 >> 5) + w] = bits;
            }
            __syncthreads();
        }

        // ---- p3: 2 tiles ----
        #pragma unroll
        for (int pt = 0; pt < 2; ++pt) {
            const int sub = ab * 2 + pt;
            const int t0 = (sub >> 3) * 64;
            const int e0 = (sub & 7) * 64;
            const int ex = tid & 63;
            const int ty = tid >> 6;
            #pragma unroll
            for (int k = 0; k < 8; ++k) {
                int tl = ty * 8 + k;
                ldsb[tl][ex] = (A3[(size_t)(t0 + tl) * EC + e0 + ex] != 0) ? 1u : 0u;
            }
            __syncthreads();
            if (tid < 128) {
                const int el = tid & 63;
                const int w  = tid >> 6;
                uint32_t bits = 0;
                #pragma unroll
                for (int b = 0; b < 32; ++b) bits |= ldsb[w * 32 + b][el] << b;
                PT3[(size_t)(e0 + el) * 128 + (t0 >> 5) + w] = bits;
            }
            __syncthreads();
        }

        // ---- k2a: colsum of 16 rows (2 halves x 8 rows, 256 d-threads) ----
        {
            const int d = tid & 255;
            const int h = tid >> 8;  // 0 or 1
            const float* base = emb + (size_t)N2C * DN;
            const int r0 = ab * 16 + h * 8;
            float s = 0.f;
            #pragma unroll
            for (int r = r0; r < r0 + 8; ++r) s += base[(size_t)r * DN + d];
            atomicAdd(&S[d], s);
        }
    }
}

// ---------------------------------------------------------------------------
// k3_dense: new_common[t,d] = (sub+S)*(1 - S/deg1) + A2f^T@new2 + (512-deg2)
// Block 256 thr = 4 wave-groups x 64 d4; each group owns 4 t. Grid 256.
// Dense bit-FMA over e; one coalesced 1KB spec row load serves 16 FMAs.
// ---------------------------------------------------------------------------
__global__ __launch_bounds__(256) void k3_dense(
    const float* __restrict__ emb, const uint32_t* __restrict__ PT2,
    const float* __restrict__ S, const float* __restrict__ deg1,
    float* out)
{
    const int d4 = threadIdx.x & 63;
    const int tg = threadIdx.x >> 6;
    const int t0 = blockIdx.x * 16 + tg * 4;
    const float4* spec = (const float4*)out;  // new2, rows 0..511
    const uint32_t* pt = PT2 + (size_t)t0 * 16;

    float4 a0 = {0,0,0,0}, a1 = {0,0,0,0}, a2 = {0,0,0,0}, a3 = {0,0,0,0};
    int c0 = 0, c1 = 0, c2 = 0, c3 = 0;

    for (int ec = 0; ec < 16; ++ec) {
        const uint32_t w0 = pt[ec];
        const uint32_t w1 = pt[16 + ec];
        const uint32_t w2 = pt[32 + ec];
        const uint32_t w3 = pt[48 + ec];
        c0 += __popc(w0); c1 += __popc(w1); c2 += __popc(w2); c3 += __popc(w3);
        const float4* sp = spec + (size_t)ec * 32 * 64 + d4;
        #pragma unroll
        for (int b = 0; b < 32; ++b) {
            float4 v = sp[b * 64];
            float m0 = (float)((w0 >> b) & 1u);
            float m1 = (float)((w1 >> b) & 1u);
            float m2 = (float)((w2 >> b) & 1u);
            float m3 = (float)((w3 >> b) & 1u);
            a0.x = fmaf(m0, v.x, a0.x); a0.y = fmaf(m0, v.y, a0.y);
            a0.z = fmaf(m0, v.z, a0.z); a0.w = fmaf(m0, v.w, a0.w);
            a1.x = fmaf(m1, v.x, a1.x); a1.y = fmaf(m1, v.y, a1.y);
            a1.z = fmaf(m1, v.z, a1.z); a1.w = fmaf(m1, v.w, a1.w);
            a2.x = fmaf(m2, v.x, a2.x); a2.y = fmaf(m2, v.y, a2.y);
            a2.z = fmaf(m2, v.z, a2.z); a2.w = fmaf(m2, v.w, a2.w);
            a3.x = fmaf(m3, v.x, a3.x); a3.y = fmaf(m3, v.y, a3.y);
            a3.z = fmaf(m3, v.z, a3.z); a3.w = fmaf(m3, v.w, a3.w);
        }
    }

    const float4 Sv = ((const float4*)S)[d4];
#define K3_EPI(ak, ck, kk) { \
    const int t = t0 + kk; \
    const float inv = 1.0f / deg1[t]; \
    const float addc = (float)(EC - ck); \
    const float4 sub = ((const float4*)emb)[(size_t)(N2C + t) * 64 + d4]; \
    float4 o; \
    o.x = (sub.x + Sv.x) * (1.0f - Sv.x * inv) + ak.x + addc; \
    o.y = (sub.y + Sv.y) * (1.0f - Sv.y * inv) + ak.y + addc; \
    o.z = (sub.z + Sv.z) * (1.0f - Sv.z * inv) + ak.z + addc; \
    o.w = (sub.w + Sv.w) * (1.0f - Sv.w * inv) + ak.w + addc; \
    ((float4*)out)[(size_t)(N2C + t) * 64 + d4] = o; }
    K3_EPI(a0, c0, 0)
    K3_EPI(a1, c1, 1)
    K3_EPI(a2, c2, 2)
    K3_EPI(a3, c3, 3)
#undef K3_EPI
}

// ---------------------------------------------------------------------------
// k4_part: P[chunk][e][d] = sum over chunk's 512 t of bit3(t,e)*nc[t][d].
// Grid = 32 e-tiles x 8 chunks = 256 blocks (1/CU).
// Block 256 thr = 4 wave-groups x 64 d4; each group owns 4 e.
// ---------------------------------------------------------------------------
__global__ __launch_bounds__(256) void k4_part(
    const uint32_t* __restrict__ PT3, const float* __restrict__ out,
    float* __restrict__ P)
{
    const int d4    = threadIdx.x & 63;
    const int es    = threadIdx.x >> 6;   // 0..3
    const int etile = blockIdx.x >> 3;    // 0..31
    const int chunk = blockIdx.x & 7;     // 0..7
    const int e0 = etile * 16 + es * 4;
    const float4* nc = (const float4*)(out + (size_t)N2C * DN);

    float4 a0 = {0,0,0,0}, a1 = {0,0,0,0}, a2 = {0,0,0,0}, a3 = {0,0,0,0};

    for (int w = 0; w < 16; ++w) {
        const uint32_t m0 = PT3[(size_t)(e0 + 0) * 128 + chunk * 16 + w];
        const uint32_t m1 = PT3[(size_t)(e0 + 1) * 128 + chunk * 16 + w];
        const uint32_t m2 = PT3[(size_t)(e0 + 2) * 128 + chunk * 16 + w];
        const uint32_t m3 = PT3[(size_t)(e0 + 3) * 128 + chunk * 16 + w];
        const float4* np = nc + (size_t)((chunk * 16 + w) * 32) * 64 + d4;
        #pragma unroll
        for (int b = 0; b < 32; ++b) {
            float4 v = np[b * 64];
            float f0 = (float)((m0 >> b) & 1u);
            float f1 = (float)((m1 >> b) & 1u);
            float f2 = (float)((m2 >> b) & 1u);
            float f3 = (float)((m3 >> b) & 1u);
            a0.x = fmaf(f0, v.x, a0.x); a0.y = fmaf(f0, v.y, a0.y);
            a0.z = fmaf(f0, v.z, a0.z); a0.w = fmaf(f0, v.w, a0.w);
            a1.x = fmaf(f1, v.x, a1.x); a1.y = fmaf(f1, v.y, a1.y);
            a1.z = fmaf(f1, v.z, a1.z); a1.w = fmaf(f1, v.w, a1.w);
            a2.x = fmaf(f2, v.x, a2.x); a2.y = fmaf(f2, v.y, a2.y);
            a2.z = fmaf(f2, v.z, a2.z); a2.w = fmaf(f2, v.w, a2.w);
            a3.x = fmaf(f3, v.x, a3.x); a3.y = fmaf(f3, v.y, a3.y);
            a3.z = fmaf(f3, v.z, a3.z); a3.w = fmaf(f3, v.w, a3.w);
        }
    }
    float4* Pp = (float4*)P;
    Pp[((size_t)chunk * EC + e0 + 0) * 64 + d4] = a0;
    Pp[((size_t)chunk * EC + e0 + 1) * 64 + d4] = a1;
    Pp[((size_t)chunk * EC + e0 + 2) * 64 + d4] = a2;
    Pp[((size_t)chunk * EC + e0 + 3) * 64 + d4] = a3;
}

// ---------------------------------------------------------------------------
// k4_fin: combine 8 partials, deg3 via popcount of PT3[e][*],
// new_spec[e,d] = new2[e,d]*(1 - (msg3+4096-deg3)/(1+deg3)). Wave per e.
// ---------------------------------------------------------------------------
__global__ __launch_bounds__(256) void k4_fin(
    const uint32_t* __restrict__ PT3, const float* __restrict__ P,
    float* out)
{
    const int d4 = threadIdx.x & 63;
    const int es = threadIdx.x >> 6;
    const int e  = blockIdx.x * 4 + es;
    const float4* Pp = (const float4*)P;

    float4 s = {0.f, 0.f, 0.f, 0.f};
    #pragma unroll
    for (int c = 0; c < 8; ++c) {
        float4 v = Pp[((size_t)c * EC + e) * 64 + d4];
        s.x += v.x; s.y += v.y; s.z += v.z; s.w += v.w;
    }

    int c = __popc(PT3[(size_t)e * 128 + 2 * d4]) +
            __popc(PT3[(size_t)e * 128 + 2 * d4 + 1]);
    #pragma unroll
    for (int off = 32; off > 0; off >>= 1) c += __shfl_xor(c, off, 64);

    const float msg_add = (float)(TC - c);
    const float inv = 1.0f / (1.0f + (float)c);
    float4 cur = ((const float4*)out)[(size_t)e * 64 + d4];
    float4 o;
    o.x = cur.x * (1.0f - (s.x + msg_add) * inv);
    o.y = cur.y * (1.0f - (s.y + msg_add) * inv);
    o.z = cur.z * (1.0f - (s.z + msg_add) * inv);
    o.w = cur.w * (1.0f - (s.w + msg_add) * inv);
    ((float4*)out)[(size_t)e * 64 + d4] = o;
}

extern "C" void kernel_launch(void* const* d_in, const int* in_sizes, int n_in,
                              void* d_out, int out_size, void* d_ws, size_t ws_size,
                              hipStream_t stream) {
    const float* emb = (const float*)d_in[0];
    const float* W2  = (const float*)d_in[1];
    const float* R2  = (const float*)d_in[2];
    const int*   A1  = (const int*)d_in[3];
    const int*   A2  = (const int*)d_in[4];
    const int*   A3  = (const int*)d_in[5];
    float* out = (float*)d_out;

    float*    S    = (float*)d_ws;                    // 256 floats
    float*    deg1 = S + DN;                          // 4096 floats
    uint32_t* PT2  = (uint32_t*)(deg1 + TC);          // 4096*16 words (256 KB)
    uint32_t* PT3  = PT2 + (size_t)TC * 16;           // 512*128 words (256 KB)
    float*    P    = (float*)(PT3 + (size_t)EC * 128);// 8*512*256 floats (4 MB)

    hipMemsetAsync(d_ws, 0, DN * sizeof(float), stream);

    prep_fused<<<B_K1 + B_A, 512, 0, stream>>>(emb, W2, R2, A1, A2, A3,
                                               out, S, deg1, PT2, PT3);
    k3_dense<<<TC / 16, 256, 0, stream>>>(emb, PT2, S, deg1, out);
    k4_part<<<256, 256, 0, stream>>>(PT3, out, P);
    k4_fin<<<EC / 4, 256, 0, stream>>>(PT3, P, out);
}

// Round 6
// 212.386 us; speedup vs baseline: 2.4058x; 1.0165x over previous
//
#include <hip/hip_runtime.h>
#include <stdint.h>

// Problem constants
#define DN 256   // D
#define N2C 512  // N2 (= E)
#define TC 4096  // T
#define EC 512   // E

// prep grid: 256 A-blocks FIRST (so the 80 MB A1/A2/A3 stream overlaps k1's
// start), then 2048 k1 partial blocks (j,quarter). All 256-thread blocks,
// __launch_bounds__(256,8) -> 8 blocks/CU = 32 waves/CU for the k1 stream.
#define B_A   256
#define B_TOT (B_A + 2048)

// ---------------------------------------------------------------------------
// prep_fused:
//  A-block ab (bids 0..255): 16 rows k2b (deg1), 2 tiles p2 (PT2),
//      2 tiles p3 (PT3), 16 rows k2a colsum (S, atomicAdd into zeroed S).
//  k1-block (bids 256..2303): kb = bid-256, j = kb>>2, q = kb&3.
//      Ppart[kb][d] = sum_{i in [q*128,q*128+128)} x2[i,d]*W2[j,i,d] + R2[j,i,d]
//      Wave g streams 32 contiguous KB of W and R. 4-wave LDS reduce.
// ---------------------------------------------------------------------------
__global__ __launch_bounds__(256, 8) void prep_fused(
    const float* __restrict__ emb, const float* __restrict__ W2,
    const float* __restrict__ R2, const int* __restrict__ A1,
    const int* __restrict__ A2, const int* __restrict__ A3,
    float* __restrict__ S, float* __restrict__ deg1,
    uint32_t* __restrict__ PT2, uint32_t* __restrict__ PT3,
    float* __restrict__ Ppart)
{
    __shared__ __align__(16) char smem[64 * 65 * 4];  // union: ldsb / red
    uint32_t (*ldsb)[65] = (uint32_t (*)[65])smem;
    float4   (*red)[64]  = (float4 (*)[64])smem;

    const int bid = blockIdx.x;
    const int tid = threadIdx.x;

    if (bid >= B_A) {
        // ---- k1 partial ----
        const int kb  = bid - B_A;
        const int j   = kb >> 2;
        const int q   = kb & 3;
        const int d4  = tid & 63;
        const int grp = tid >> 6;   // 0..3
        const float4* W = (const float4*)(W2 + (size_t)j * N2C * DN);
        const float4* R = (const float4*)(R2 + (size_t)j * N2C * DN);
        const float4* X = (const float4*)emb;

        float ax = 0.f, ay = 0.f, az = 0.f, aw = 0.f;
        const int i0 = q * 128 + grp * 32;
        #pragma unroll 4
        for (int i = i0; i < i0 + 32; ++i) {
            float4 w = W[i * 64 + d4];
            float4 r = R[i * 64 + d4];
            float4 x = X[i * 64 + d4];
            ax += x.x * w.x + r.x;
            ay += x.y * w.y + r.y;
            az += x.z * w.z + r.z;
            aw += x.w * w.w + r.w;
        }
        float4 mine; mine.x = ax; mine.y = ay; mine.z = az; mine.w = aw;
        red[grp][d4] = mine;
        __syncthreads();
        if (grp == 0) {
            float4 v0 = red[0][d4], v1 = red[1][d4];
            float4 v2 = red[2][d4], v3 = red[3][d4];
            float4 o;
            o.x = (v0.x + v1.x) + (v2.x + v3.x);
            o.y = (v0.y + v1.y) + (v2.y + v3.y);
            o.z = (v0.z + v1.z) + (v2.z + v3.z);
            o.w = (v0.w + v1.w) + (v2.w + v3.w);
            ((float4*)Ppart)[(size_t)kb * 64 + d4] = o;
        }
    } else {
        const int ab = bid;  // 0..255

        // ---- k2b: deg1 for 16 rows (wave per row, 4 passes) ----
        {
            const int lane = tid & 63;
            for (int it = 0; it < 4; ++it) {
                const int row = ab * 16 + it * 4 + (tid >> 6);
                const int4* p = (const int4*)(A1 + (size_t)row * TC);
                int cnt = 0;
                #pragma unroll 4
                for (int k = 0; k < 16; ++k) {
                    int4 v = p[k * 64 + lane];
                    cnt += (v.x != 0) + (v.y != 0) + (v.z != 0) + (v.w != 0);
                }
                #pragma unroll
                for (int off = 32; off > 0; off >>= 1)
                    cnt += __shfl_down(cnt, off, 64);
                if (lane == 0) deg1[row] = 1.0f + (float)cnt;
            }
        }

        // ---- p2: 2 tiles ----
        for (int pt = 0; pt < 2; ++pt) {
            const int sub = ab * 2 + pt;
            const int e0 = (sub & 7) * 64;
            const int t0 = (sub >> 3) * 64;
            const int tx = tid & 63;
            const int ty = tid >> 6;   // 0..3
            __syncthreads();
            #pragma unroll 4
            for (int k = 0; k < 16; ++k) {
                int el = ty * 16 + k;
                ldsb[el][tx] = (A2[(size_t)(e0 + el) * TC + t0 + tx] != 0) ? 1u : 0u;
            }
            __syncthreads();
            if (tid < 128) {
                const int tl = tid & 63;
                const int w  = tid >> 6;
                uint32_t bits = 0;
                #pragma unroll
                for (int b = 0; b < 32; ++b) bits |= ldsb[w * 32 + b][tl] << b;
                PT2[(size_t)(t0 + tl) * 16 + (e0 >> 5) + w] = bits;
            }
        }

        // ---- p3: 2 tiles ----
        for (int pt = 0; pt < 2; ++pt) {
            const int sub = ab * 2 + pt;
            const int t0 = (sub >> 3) * 64;
            const int e0 = (sub & 7) * 64;
            const int ex = tid & 63;
            const int ty = tid >> 6;
            __syncthreads();
            #pragma unroll 4
            for (int k = 0; k < 16; ++k) {
                int tl = ty * 16 + k;
                ldsb[tl][ex] = (A3[(size_t)(t0 + tl) * EC + e0 + ex] != 0) ? 1u : 0u;
            }
            __syncthreads();
            if (tid < 128) {
                const int el = tid & 63;
                const int w  = tid >> 6;
                uint32_t bits = 0;
                #pragma unroll
                for (int b = 0; b < 32; ++b) bits |= ldsb[w * 32 + b][el] << b;
                PT3[(size_t)(e0 + el) * 128 + (t0 >> 5) + w] = bits;
            }
        }

        // ---- k2a: colsum of 16 rows, 256 d-threads ----
        {
            const int d = tid;
            const float* base = emb + (size_t)N2C * DN;
            const int r0 = ab * 16;
            float s = 0.f;
            #pragma unroll 4
            for (int r = r0; r < r0 + 16; ++r) s += base[(size_t)r * DN + d];
            atomicAdd(&S[d], s);
        }
    }
}

// ---------------------------------------------------------------------------
// k1_combine: out[j,d] = Ppart[j*4+0..3][d] + x2[j,d].  128 blocks x 256 thr.
// ---------------------------------------------------------------------------
__global__ __launch_bounds__(256) void k1_combine(
    const float* __restrict__ emb, const float* __restrict__ Ppart,
    float* __restrict__ out)
{
    const int jj = blockIdx.x * 4 + (threadIdx.x >> 6);
    const int d4 = threadIdx.x & 63;
    const float4* Pp = (const float4*)Ppart;
    float4 v0 = Pp[(size_t)(jj * 4 + 0) * 64 + d4];
    float4 v1 = Pp[(size_t)(jj * 4 + 1) * 64 + d4];
    float4 v2 = Pp[(size_t)(jj * 4 + 2) * 64 + d4];
    float4 v3 = Pp[(size_t)(jj * 4 + 3) * 64 + d4];
    float4 x  = ((const float4*)emb)[(size_t)jj * 64 + d4];
    float4 o;
    o.x = (v0.x + v1.x) + (v2.x + v3.x) + x.x;
    o.y = (v0.y + v1.y) + (v2.y + v3.y) + x.y;
    o.z = (v0.z + v1.z) + (v2.z + v3.z) + x.z;
    o.w = (v0.w + v1.w) + (v2.w + v3.w) + x.w;
    ((float4*)out)[(size_t)jj * 64 + d4] = o;
}

// ---------------------------------------------------------------------------
// k3_dense: new_common[t,d] = (sub+S)*(1 - S/deg1) + A2f^T@new2 + (512-deg2)
// Block 256 thr = 4 wave-groups x 64 d4; each group owns 2 t. Grid 512 (2/CU).
// Dense bit-FMA over e; one coalesced 1KB spec row load serves 8 FMAs.
// ---------------------------------------------------------------------------
__global__ __launch_bounds__(256) void k3_dense(
    const float* __restrict__ emb, const uint32_t* __restrict__ PT2,
    const float* __restrict__ S, const float* __restrict__ deg1,
    float* out)
{
    const int d4 = threadIdx.x & 63;
    const int tg = threadIdx.x >> 6;
    const int t0 = blockIdx.x * 8 + tg * 2;
    const float4* spec = (const float4*)out;  // new2, rows 0..511
    const uint32_t* pt = PT2 + (size_t)t0 * 16;

    float4 a0 = {0,0,0,0}, a1 = {0,0,0,0};
    int c0 = 0, c1 = 0;

    for (int ec = 0; ec < 16; ++ec) {
        const uint32_t w0 = pt[ec];
        const uint32_t w1 = pt[16 + ec];
        c0 += __popc(w0); c1 += __popc(w1);
        const float4* sp = spec + (size_t)ec * 32 * 64 + d4;
        #pragma unroll
        for (int b = 0; b < 32; ++b) {
            float4 v = sp[b * 64];
            float m0 = (float)((w0 >> b) & 1u);
            float m1 = (float)((w1 >> b) & 1u);
            a0.x = fmaf(m0, v.x, a0.x); a0.y = fmaf(m0, v.y, a0.y);
            a0.z = fmaf(m0, v.z, a0.z); a0.w = fmaf(m0, v.w, a0.w);
            a1.x = fmaf(m1, v.x, a1.x); a1.y = fmaf(m1, v.y, a1.y);
            a1.z = fmaf(m1, v.z, a1.z); a1.w = fmaf(m1, v.w, a1.w);
        }
    }

    const float4 Sv = ((const float4*)S)[d4];
#define K3_EPI(ak, ck, kk) { \
    const int t = t0 + kk; \
    const float inv = 1.0f / deg1[t]; \
    const float addc = (float)(EC - ck); \
    const float4 sub = ((const float4*)emb)[(size_t)(N2C + t) * 64 + d4]; \
    float4 o; \
    o.x = (sub.x + Sv.x) * (1.0f - Sv.x * inv) + ak.x + addc; \
    o.y = (sub.y + Sv.y) * (1.0f - Sv.y * inv) + ak.y + addc; \
    o.z = (sub.z + Sv.z) * (1.0f - Sv.z * inv) + ak.z + addc; \
    o.w = (sub.w + Sv.w) * (1.0f - Sv.w * inv) + ak.w + addc; \
    ((float4*)out)[(size_t)(N2C + t) * 64 + d4] = o; }
    K3_EPI(a0, c0, 0)
    K3_EPI(a1, c1, 1)
#undef K3_EPI
}

// ---------------------------------------------------------------------------
// k4_part: P[chunk][e][d] = sum over chunk's 512 t of bit3(t,e)*nc[t][d].
// Grid = 64 e-tiles x 8 chunks = 512 blocks (2/CU).
// Block 256 thr = 4 wave-groups x 64 d4; each group owns 2 e.
// ---------------------------------------------------------------------------
__global__ __launch_bounds__(256) void k4_part(
    const uint32_t* __restrict__ PT3, const float* __restrict__ out,
    float* __restrict__ P)
{
    const int d4    = threadIdx.x & 63;
    const int es    = threadIdx.x >> 6;   // 0..3
    const int etile = blockIdx.x >> 3;    // 0..63
    const int chunk = blockIdx.x & 7;     // 0..7
    const int e0 = etile * 8 + es * 2;
    const float4* nc = (const float4*)(out + (size_t)N2C * DN);

    float4 a0 = {0,0,0,0}, a1 = {0,0,0,0};

    for (int w = 0; w < 16; ++w) {
        const uint32_t m0 = PT3[(size_t)(e0 + 0) * 128 + chunk * 16 + w];
        const uint32_t m1 = PT3[(size_t)(e0 + 1) * 128 + chunk * 16 + w];
        const float4* np = nc + (size_t)((chunk * 16 + w) * 32) * 64 + d4;
        #pragma unroll
        for (int b = 0; b < 32; ++b) {
            float4 v = np[b * 64];
            float f0 = (float)((m0 >> b) & 1u);
            float f1 = (float)((m1 >> b) & 1u);
            a0.x = fmaf(f0, v.x, a0.x); a0.y = fmaf(f0, v.y, a0.y);
            a0.z = fmaf(f0, v.z, a0.z); a0.w = fmaf(f0, v.w, a0.w);
            a1.x = fmaf(f1, v.x, a1.x); a1.y = fmaf(f1, v.y, a1.y);
            a1.z = fmaf(f1, v.z, a1.z); a1.w = fmaf(f1, v.w, a1.w);
        }
    }
    float4* Pp = (float4*)P;
    Pp[((size_t)chunk * EC + e0 + 0) * 64 + d4] = a0;
    Pp[((size_t)chunk * EC + e0 + 1) * 64 + d4] = a1;
}

// ---------------------------------------------------------------------------
// k4_fin: combine 8 partials, deg3 via popcount of PT3[e][*],
// new_spec[e,d] = new2[e,d]*(1 - (msg3+4096-deg3)/(1+deg3)). Wave per e.
// ---------------------------------------------------------------------------
__global__ __launch_bounds__(256) void k4_fin(
    const uint32_t* __restrict__ PT3, const float* __restrict__ P,
    float* out)
{
    const int d4 = threadIdx.x & 63;
    const int es = threadIdx.x >> 6;
    const int e  = blockIdx.x * 4 + es;
    const float4* Pp = (const float4*)P;

    float4 s = {0.f, 0.f, 0.f, 0.f};
    #pragma unroll
    for (int c = 0; c < 8; ++c) {
        float4 v = Pp[((size_t)c * EC + e) * 64 + d4];
        s.x += v.x; s.y += v.y; s.z += v.z; s.w += v.w;
    }

    int c = __popc(PT3[(size_t)e * 128 + 2 * d4]) +
            __popc(PT3[(size_t)e * 128 + 2 * d4 + 1]);
    #pragma unroll
    for (int off = 32; off > 0; off >>= 1) c += __shfl_xor(c, off, 64);

    const float msg_add = (float)(TC - c);
    const float inv = 1.0f / (1.0f + (float)c);
    float4 cur = ((const float4*)out)[(size_t)e * 64 + d4];
    float4 o;
    o.x = cur.x * (1.0f - (s.x + msg_add) * inv);
    o.y = cur.y * (1.0f - (s.y + msg_add) * inv);
    o.z = cur.z * (1.0f - (s.z + msg_add) * inv);
    o.w = cur.w * (1.0f - (s.w + msg_add) * inv);
    ((float4*)out)[(size_t)e * 64 + d4] = o;
}

extern "C" void kernel_launch(void* const* d_in, const int* in_sizes, int n_in,
                              void* d_out, int out_size, void* d_ws, size_t ws_size,
                              hipStream_t stream) {
    const float* emb = (const float*)d_in[0];
    const float* W2  = (const float*)d_in[1];
    const float* R2  = (const float*)d_in[2];
    const int*   A1  = (const int*)d_in[3];
    const int*   A2  = (const int*)d_in[4];
    const int*   A3  = (const int*)d_in[5];
    float* out = (float*)d_out;

    float*    S    = (float*)d_ws;                    // 256 floats
    float*    deg1 = S + DN;                          // 4096 floats
    uint32_t* PT2  = (uint32_t*)(deg1 + TC);          // 4096*16 words (256 KB)
    uint32_t* PT3  = PT2 + (size_t)TC * 16;           // 512*128 words (256 KB)
    float*    P    = (float*)(PT3 + (size_t)EC * 128);// 8*512*256 floats (4 MB)
    float*    Ppart = P;   // aliases P: Ppart (2 MB) dead before k4_part runs

    hipMemsetAsync(d_ws, 0, DN * sizeof(float), stream);

    prep_fused<<<B_TOT, 256, 0, stream>>>(emb, W2, R2, A1, A2, A3,
                                          S, deg1, PT2, PT3, Ppart);
    k1_combine<<<N2C / 4, 256, 0, stream>>>(emb, Ppart, out);
    k3_dense<<<TC / 8, 256, 0, stream>>>(emb, PT2, S, deg1, out);
    k4_part<<<512, 256, 0, stream>>>(PT3, out, P);
    k4_fin<<<EC / 4, 256, 0, stream>>>(PT3, P, out);
}

// Round 7
// 210.020 us; speedup vs baseline: 2.4329x; 1.0113x over previous
//
#include <hip/hip_runtime.h>
#include <stdint.h>

// Problem constants
#define DN 256   // D
#define N2C 512  // N2 (= E)
#define TC 4096  // T
#define EC 512   // E

// prep grid: 256 A-blocks first, then 2048 k1 blocks:
//   kb = bid - B_A; type = kb&1 (0=W-FMA, 1=R-sum); idx = kb>>1;
//   j = idx>>1, h = idx&1 (which half of i-range).
// Each k1 block reads ONE contiguous 256 KB stream (W half-row or R half-row)
// — no per-wave stream mixing. 256-thr blocks, 8/CU.
#define B_A   256
#define B_K1  2048
#define B_TOT (B_A + B_K1)

// ---------------------------------------------------------------------------
// prep_fused:
//  A-block ab (bids 0..255): 16 rows k2b (deg1), 2 tiles p2 (PT2),
//      2 tiles p3 (PT3), 16 rows k2a colsum (S, atomicAdd into zeroed S).
//  W-block (j,h): Wpart[j*2+h][d] = sum_{i in half h} x2[i,d]*W2[j,i,d]
//  R-block (j,h): Rpart[j*2+h][d] = sum_{i in half h} R2[j,i,d]   (pure stream)
// ---------------------------------------------------------------------------
__global__ __launch_bounds__(256, 8) void prep_fused(
    const float* __restrict__ emb, const float* __restrict__ W2,
    const float* __restrict__ R2, const int* __restrict__ A1,
    const int* __restrict__ A2, const int* __restrict__ A3,
    float* __restrict__ S, float* __restrict__ deg1,
    uint32_t* __restrict__ PT2, uint32_t* __restrict__ PT3,
    float* __restrict__ Wpart, float* __restrict__ Rpart)
{
    __shared__ __align__(16) char smem[64 * 65 * 4];  // union: ldsb / red
    uint32_t (*ldsb)[65] = (uint32_t (*)[65])smem;
    float4   (*red)[64]  = (float4 (*)[64])smem;

    const int bid = blockIdx.x;
    const int tid = threadIdx.x;

    if (bid >= B_A) {
        const int kb   = bid - B_A;
        const int type = kb & 1;
        const int idx  = kb >> 1;     // 0..1023
        const int j    = idx >> 1;
        const int h    = idx & 1;
        const int d4   = tid & 63;
        const int grp  = tid >> 6;    // 0..3
        const int i0   = h * 256 + grp * 64;

        float4 acc = {0.f, 0.f, 0.f, 0.f};
        if (type == 0) {
            // ---- W-FMA block: stream W half-row; X served from L2/L3 ----
            const float4* W = (const float4*)(W2 + (size_t)j * N2C * DN);
            const float4* X = (const float4*)emb;
            #pragma unroll 4
            for (int i = i0; i < i0 + 64; ++i) {
                float4 w = W[i * 64 + d4];
                float4 x = X[i * 64 + d4];
                acc.x = fmaf(x.x, w.x, acc.x);
                acc.y = fmaf(x.y, w.y, acc.y);
                acc.z = fmaf(x.z, w.z, acc.z);
                acc.w = fmaf(x.w, w.w, acc.w);
            }
        } else {
            // ---- R-sum block: ONE contiguous 256 KB read stream ----
            const float4* R = (const float4*)(R2 + (size_t)j * N2C * DN);
            #pragma unroll 8
            for (int i = i0; i < i0 + 64; ++i) {
                float4 r = R[i * 64 + d4];
                acc.x += r.x; acc.y += r.y; acc.z += r.z; acc.w += r.w;
            }
        }
        red[grp][d4] = acc;
        __syncthreads();
        if (grp == 0) {
            float4 v0 = red[0][d4], v1 = red[1][d4];
            float4 v2 = red[2][d4], v3 = red[3][d4];
            float4 o;
            o.x = (v0.x + v1.x) + (v2.x + v3.x);
            o.y = (v0.y + v1.y) + (v2.y + v3.y);
            o.z = (v0.z + v1.z) + (v2.z + v3.z);
            o.w = (v0.w + v1.w) + (v2.w + v3.w);
            float* dst = (type == 0) ? Wpart : Rpart;
            ((float4*)dst)[(size_t)idx * 64 + d4] = o;
        }
    } else {
        const int ab = bid;  // 0..255

        // ---- k2b: deg1 for 16 rows (wave per row, 4 passes) ----
        {
            const int lane = tid & 63;
            for (int it = 0; it < 4; ++it) {
                const int row = ab * 16 + it * 4 + (tid >> 6);
                const int4* p = (const int4*)(A1 + (size_t)row * TC);
                int cnt = 0;
                #pragma unroll 4
                for (int k = 0; k < 16; ++k) {
                    int4 v = p[k * 64 + lane];
                    cnt += (v.x != 0) + (v.y != 0) + (v.z != 0) + (v.w != 0);
                }
                #pragma unroll
                for (int off = 32; off > 0; off >>= 1)
                    cnt += __shfl_down(cnt, off, 64);
                if (lane == 0) deg1[row] = 1.0f + (float)cnt;
            }
        }

        // ---- p2: 2 tiles ----
        for (int pt = 0; pt < 2; ++pt) {
            const int sub = ab * 2 + pt;
            const int e0 = (sub & 7) * 64;
            const int t0 = (sub >> 3) * 64;
            const int tx = tid & 63;
            const int ty = tid >> 6;   // 0..3
            __syncthreads();
            #pragma unroll 4
            for (int k = 0; k < 16; ++k) {
                int el = ty * 16 + k;
                ldsb[el][tx] = (A2[(size_t)(e0 + el) * TC + t0 + tx] != 0) ? 1u : 0u;
            }
            __syncthreads();
            if (tid < 128) {
                const int tl = tid & 63;
                const int w  = tid >> 6;
                uint32_t bits = 0;
                #pragma unroll
                for (int b = 0; b < 32; ++b) bits |= ldsb[w * 32 + b][tl] << b;
                PT2[(size_t)(t0 + tl) * 16 + (e0 >> 5) + w] = bits;
            }
        }

        // ---- p3: 2 tiles ----
        for (int pt = 0; pt < 2; ++pt) {
            const int sub = ab * 2 + pt;
            const int t0 = (sub >> 3) * 64;
            const int e0 = (sub & 7) * 64;
            const int ex = tid & 63;
            const int ty = tid >> 6;
            __syncthreads();
            #pragma unroll 4
            for (int k = 0; k < 16; ++k) {
                int tl = ty * 16 + k;
                ldsb[tl][ex] = (A3[(size_t)(t0 + tl) * EC + e0 + ex] != 0) ? 1u : 0u;
            }
            __syncthreads();
            if (tid < 128) {
                const int el = tid & 63;
                const int w  = tid >> 6;
                uint32_t bits = 0;
                #pragma unroll
                for (int b = 0; b < 32; ++b) bits |= ldsb[w * 32 + b][el] << b;
                PT3[(size_t)(e0 + el) * 128 + (t0 >> 5) + w] = bits;
            }
        }

        // ---- k2a: colsum of 16 rows, 256 d-threads ----
        {
            const int d = tid;
            const float* base = emb + (size_t)N2C * DN;
            const int r0 = ab * 16;
            float s = 0.f;
            #pragma unroll 4
            for (int r = r0; r < r0 + 16; ++r) s += base[(size_t)r * DN + d];
            atomicAdd(&S[d], s);
        }
    }
}

// ---------------------------------------------------------------------------
// k1_combine: out[j,d] = Wpart[2j]+Wpart[2j+1]+Rpart[2j]+Rpart[2j+1]+x2[j,d]
// 128 blocks x 256 thr (4 j per block).
// ---------------------------------------------------------------------------
__global__ __launch_bounds__(256) void k1_combine(
    const float* __restrict__ emb, const float* __restrict__ Wpart,
    const float* __restrict__ Rpart, float* __restrict__ out)
{
    const int jj = blockIdx.x * 4 + (threadIdx.x >> 6);
    const int d4 = threadIdx.x & 63;
    const float4* Wp = (const float4*)Wpart;
    const float4* Rp = (const float4*)Rpart;
    float4 w0 = Wp[(size_t)(jj * 2 + 0) * 64 + d4];
    float4 w1 = Wp[(size_t)(jj * 2 + 1) * 64 + d4];
    float4 r0 = Rp[(size_t)(jj * 2 + 0) * 64 + d4];
    float4 r1 = Rp[(size_t)(jj * 2 + 1) * 64 + d4];
    float4 x  = ((const float4*)emb)[(size_t)jj * 64 + d4];
    float4 o;
    o.x = (w0.x + w1.x) + (r0.x + r1.x) + x.x;
    o.y = (w0.y + w1.y) + (r0.y + r1.y) + x.y;
    o.z = (w0.z + w1.z) + (r0.z + r1.z) + x.z;
    o.w = (w0.w + w1.w) + (r0.w + r1.w) + x.w;
    ((float4*)out)[(size_t)jj * 64 + d4] = o;
}

// ---------------------------------------------------------------------------
// k3_dense: new_common[t,d] = (sub+S)*(1 - S/deg1) + A2f^T@new2 + (512-deg2)
// Block 256 thr = 4 wave-groups x 64 d4; each group owns 2 t. Grid 512 (2/CU).
// ---------------------------------------------------------------------------
__global__ __launch_bounds__(256) void k3_dense(
    const float* __restrict__ emb, const uint32_t* __restrict__ PT2,
    const float* __restrict__ S, const float* __restrict__ deg1,
    float* out)
{
    const int d4 = threadIdx.x & 63;
    const int tg = threadIdx.x >> 6;
    const int t0 = blockIdx.x * 8 + tg * 2;
    const float4* spec = (const float4*)out;  // new2, rows 0..511
    const uint32_t* pt = PT2 + (size_t)t0 * 16;

    float4 a0 = {0,0,0,0}, a1 = {0,0,0,0};
    int c0 = 0, c1 = 0;

    for (int ec = 0; ec < 16; ++ec) {
        const uint32_t w0 = pt[ec];
        const uint32_t w1 = pt[16 + ec];
        c0 += __popc(w0); c1 += __popc(w1);
        const float4* sp = spec + (size_t)ec * 32 * 64 + d4;
        #pragma unroll
        for (int b = 0; b < 32; ++b) {
            float4 v = sp[b * 64];
            float m0 = (float)((w0 >> b) & 1u);
            float m1 = (float)((w1 >> b) & 1u);
            a0.x = fmaf(m0, v.x, a0.x); a0.y = fmaf(m0, v.y, a0.y);
            a0.z = fmaf(m0, v.z, a0.z); a0.w = fmaf(m0, v.w, a0.w);
            a1.x = fmaf(m1, v.x, a1.x); a1.y = fmaf(m1, v.y, a1.y);
            a1.z = fmaf(m1, v.z, a1.z); a1.w = fmaf(m1, v.w, a1.w);
        }
    }

    const float4 Sv = ((const float4*)S)[d4];
#define K3_EPI(ak, ck, kk) { \
    const int t = t0 + kk; \
    const float inv = 1.0f / deg1[t]; \
    const float addc = (float)(EC - ck); \
    const float4 sub = ((const float4*)emb)[(size_t)(N2C + t) * 64 + d4]; \
    float4 o; \
    o.x = (sub.x + Sv.x) * (1.0f - Sv.x * inv) + ak.x + addc; \
    o.y = (sub.y + Sv.y) * (1.0f - Sv.y * inv) + ak.y + addc; \
    o.z = (sub.z + Sv.z) * (1.0f - Sv.z * inv) + ak.z + addc; \
    o.w = (sub.w + Sv.w) * (1.0f - Sv.w * inv) + ak.w + addc; \
    ((float4*)out)[(size_t)(N2C + t) * 64 + d4] = o; }
    K3_EPI(a0, c0, 0)
    K3_EPI(a1, c1, 1)
#undef K3_EPI
}

// ---------------------------------------------------------------------------
// k4_part: P[chunk][e][d] = sum over chunk's 512 t of bit3(t,e)*nc[t][d].
// Grid = 64 e-tiles x 8 chunks = 512 blocks (2/CU).
// ---------------------------------------------------------------------------
__global__ __launch_bounds__(256) void k4_part(
    const uint32_t* __restrict__ PT3, const float* __restrict__ out,
    float* __restrict__ P)
{
    const int d4    = threadIdx.x & 63;
    const int es    = threadIdx.x >> 6;   // 0..3
    const int etile = blockIdx.x >> 3;    // 0..63
    const int chunk = blockIdx.x & 7;     // 0..7
    const int e0 = etile * 8 + es * 2;
    const float4* nc = (const float4*)(out + (size_t)N2C * DN);

    float4 a0 = {0,0,0,0}, a1 = {0,0,0,0};

    for (int w = 0; w < 16; ++w) {
        const uint32_t m0 = PT3[(size_t)(e0 + 0) * 128 + chunk * 16 + w];
        const uint32_t m1 = PT3[(size_t)(e0 + 1) * 128 + chunk * 16 + w];
        const float4* np = nc + (size_t)((chunk * 16 + w) * 32) * 64 + d4;
        #pragma unroll
        for (int b = 0; b < 32; ++b) {
            float4 v = np[b * 64];
            float f0 = (float)((m0 >> b) & 1u);
            float f1 = (float)((m1 >> b) & 1u);
            a0.x = fmaf(f0, v.x, a0.x); a0.y = fmaf(f0, v.y, a0.y);
            a0.z = fmaf(f0, v.z, a0.z); a0.w = fmaf(f0, v.w, a0.w);
            a1.x = fmaf(f1, v.x, a1.x); a1.y = fmaf(f1, v.y, a1.y);
            a1.z = fmaf(f1, v.z, a1.z); a1.w = fmaf(f1, v.w, a1.w);
        }
    }
    float4* Pp = (float4*)P;
    Pp[((size_t)chunk * EC + e0 + 0) * 64 + d4] = a0;
    Pp[((size_t)chunk * EC + e0 + 1) * 64 + d4] = a1;
}

// ---------------------------------------------------------------------------
// k4_fin: combine 8 partials, deg3 via popcount of PT3[e][*],
// new_spec[e,d] = new2[e,d]*(1 - (msg3+4096-deg3)/(1+deg3)). Wave per e.
// ---------------------------------------------------------------------------
__global__ __launch_bounds__(256) void k4_fin(
    const uint32_t* __restrict__ PT3, const float* __restrict__ P,
    float* out)
{
    const int d4 = threadIdx.x & 63;
    const int es = threadIdx.x >> 6;
    const int e  = blockIdx.x * 4 + es;
    const float4* Pp = (const float4*)P;

    float4 s = {0.f, 0.f, 0.f, 0.f};
    #pragma unroll
    for (int c = 0; c < 8; ++c) {
        float4 v = Pp[((size_t)c * EC + e) * 64 + d4];
        s.x += v.x; s.y += v.y; s.z += v.z; s.w += v.w;
    }

    int c = __popc(PT3[(size_t)e * 128 + 2 * d4]) +
            __popc(PT3[(size_t)e * 128 + 2 * d4 + 1]);
    #pragma unroll
    for (int off = 32; off > 0; off >>= 1) c += __shfl_xor(c, off, 64);

    const float msg_add = (float)(TC - c);
    const float inv = 1.0f / (1.0f + (float)c);
    float4 cur = ((const float4*)out)[(size_t)e * 64 + d4];
    float4 o;
    o.x = cur.x * (1.0f - (s.x + msg_add) * inv);
    o.y = cur.y * (1.0f - (s.y + msg_add) * inv);
    o.z = cur.z * (1.0f - (s.z + msg_add) * inv);
    o.w = cur.w * (1.0f - (s.w + msg_add) * inv);
    ((float4*)out)[(size_t)e * 64 + d4] = o;
}

extern "C" void kernel_launch(void* const* d_in, const int* in_sizes, int n_in,
                              void* d_out, int out_size, void* d_ws, size_t ws_size,
                              hipStream_t stream) {
    const float* emb = (const float*)d_in[0];
    const float* W2  = (const float*)d_in[1];
    const float* R2  = (const float*)d_in[2];
    const int*   A1  = (const int*)d_in[3];
    const int*   A2  = (const int*)d_in[4];
    const int*   A3  = (const int*)d_in[5];
    float* out = (float*)d_out;

    float*    S    = (float*)d_ws;                    // 256 floats
    float*    deg1 = S + DN;                          // 4096 floats
    uint32_t* PT2  = (uint32_t*)(deg1 + TC);          // 4096*16 words (256 KB)
    uint32_t* PT3  = PT2 + (size_t)TC * 16;           // 512*128 words (256 KB)
    float*    P    = (float*)(PT3 + (size_t)EC * 128);// 8*512*256 floats (4 MB)
    // Wpart/Rpart (1 MB each) alias P: dead before k4_part overwrites P.
    float*    Wpart = P;
    float*    Rpart = P + (size_t)1024 * DN;

    hipMemsetAsync(d_ws, 0, DN * sizeof(float), stream);

    prep_fused<<<B_TOT, 256, 0, stream>>>(emb, W2, R2, A1, A2, A3,
                                          S, deg1, PT2, PT3, Wpart, Rpart);
    k1_combine<<<N2C / 4, 256, 0, stream>>>(emb, Wpart, Rpart, out);
    k3_dense<<<TC / 8, 256, 0, stream>>>(emb, PT2, S, deg1, out);
    k4_part<<<512, 256, 0, stream>>>(PT3, out, P);
    k4_fin<<<EC / 4, 256, 0, stream>>>(PT3, P, out);
}